// Round 11
// baseline (69.702 us; speedup 1.0000x reference)
//
#include <hip/hip_runtime.h>

#define DIM 256
#define NSEG 2048
#define NATOMS 262144
#define SUB 8                         /* atoms per subtile (R7/R10-proven) */
#define NSUB 8
#define TA (SUB * NSUB)               /* 64 atoms per wave-tile */
#define NTILES (NATOMS / TA)          /* 4096, exact */
#define SLOTS (NSEG + NTILES)         /* 6144 */
#define WPB 4                         /* waves per block */
#define NBLK (NTILES / WPB)           /* 1024 = exactly 4 blocks/CU */

// index_list may arrive as int64 (reference dtype) or int32. Detect on-device:
// for int64, word[1] is the high half of offset 0 (== 0); for int32, word[1]
// is the first interior offset (>= 1).
__device__ __forceinline__ long long load_off(const void* p, int i, int is64) {
  if (is64) return ((const long long*)p)[i];
  return (long long)((const int*)p)[i];
}

// Wave-wide sum, result broadcast to ALL lanes. DPP (VALU pipe) for strides
// 1,2,4,8; ds_swizzle for 16; shfl for 32. Validated R5-R10.
__device__ __forceinline__ float wave_sum_b(float v) {
  int x;
  x = __builtin_amdgcn_update_dpp(0, __float_as_int(v), 0xB1, 0xF, 0xF, true);
  v += __int_as_float(x);
  x = __builtin_amdgcn_update_dpp(0, __float_as_int(v), 0x4E, 0xF, 0xF, true);
  v += __int_as_float(x);
  x = __builtin_amdgcn_update_dpp(0, __float_as_int(v), 0x141, 0xF, 0xF, true);
  v += __int_as_float(x);
  x = __builtin_amdgcn_update_dpp(0, __float_as_int(v), 0x140, 0xF, 0xF, true);
  v += __int_as_float(x);
  v += __int_as_float(__builtin_amdgcn_ds_swizzle(__float_as_int(v), 0x401F));
  v += __shfl_xor(v, 32);
  return v;
}

// fp32 -> bf16 (RNE) pack / unpack (validated R7-R10, absmax 0.0156 << 0.0675).
__device__ __forceinline__ unsigned bf16rne(float f) {
  unsigned u = __float_as_uint(f);
  return (u + 0x7FFFu + ((u >> 16) & 1u)) >> 16;
}
__device__ __forceinline__ unsigned pack2(float a, float b) {
  return bf16rne(a) | (bf16rne(b) << 16);
}
__device__ __forceinline__ float4 unpack4(uint2 u) {
  float4 f;
  f.x = __uint_as_float(u.x << 16);
  f.y = __uint_as_float(u.x & 0xFFFF0000u);
  f.z = __uint_as_float(u.y << 16);
  f.w = __uint_as_float(u.y & 0xFFFF0000u);
  return f;
}

// s0tab[u]/s1tab[u] = segment of tile u's first/last atom (R4-R10 formulas).
__global__ void seg_of_tile(const void* __restrict__ offs_raw,
                            int* __restrict__ s0tab,
                            int* __restrict__ s1tab)
{
  int s = blockIdx.x * blockDim.x + threadIdx.x;
  if (s >= NSEG) return;
  const int is64 = (((const int*)offs_raw)[1] == 0);
  const int lo = (int)load_off(offs_raw, s, is64);
  const int hi = (int)load_off(offs_raw, s + 1, is64);
  {
    int u0 = (lo + TA - 1) / TA;
    int u1 = (hi + TA - 1) / TA - 1;
    for (int u = u0; u <= u1; ++u) s0tab[u] = s;
  }
  {
    int u0 = lo / TA;
    int u1 = hi >= TA ? (hi - TA) / TA : -1;
    for (int u = u0; u <= u1; ++u) s1tab[u] = s;
  }
}

// Online-softmax pooling (R10 structure, TA=64): 8 subtiles of 8, running
// (m,d,acc) in registers with flash rescale; A/B subtile double-buffer keeps
// 8 loads always in flight. One partial per (segment,tile) intersection.
__global__ __launch_bounds__(256, 4)
void pool_waves(const float* __restrict__ feat,
                const void* __restrict__ offs_raw,
                const float* __restrict__ Wa,
                const int* __restrict__ s0tab,
                const int* __restrict__ s1tab,
                float* __restrict__ md,
                uint2* __restrict__ accbuf)
{
  const int lane = threadIdx.x & 63;
  const int wv   = threadIdx.x >> 6;
  const int u    = blockIdx.x * WPB + wv;
  const int base = u * TA;
  const int is64 = (((const int*)offs_raw)[1] == 0);

  const float4* fg = (const float4*)feat + (size_t)base * (DIM / 4);

  float4 A[SUB], B[SUB];
#pragma unroll
  for (int k = 0; k < SUB; ++k) A[k] = fg[(size_t)k * 64 + lane];         // sub 0
#pragma unroll
  for (int k = 0; k < SUB; ++k) B[k] = fg[(size_t)(SUB + k) * 64 + lane]; // sub 1

  int s_cur = s0tab[u];
  const int s_end = s1tab[u];
  const float4 wa4 = ((const float4*)Wa)[lane];
  int hi_cur = (int)load_off(offs_raw, s_cur + 1, is64);  // uniform, L2-hot

  float m = -INFINITY, d = 0.f;
  float4 acc = make_float4(0.f, 0.f, 0.f, 0.f);

#define FLUSH_PART() do {                                                  \
    const int slot_ = s_cur + u;      /* injective: s+u monotone */        \
    accbuf[(size_t)slot_ * 64 + lane] =                                    \
        make_uint2(pack2(acc.x, acc.y), pack2(acc.z, acc.w));              \
    if (lane == 0) *((float2*)(md + 2 * slot_)) = make_float2(m, d);       \
  } while (0)

#define PROC_SUB(R, t) do {                                                \
    float lg[SUB];                                                         \
    _Pragma("unroll")                                                      \
    for (int k = 0; k < SUB; ++k) {                                        \
      float p = R[k].x * wa4.x + R[k].y * wa4.y +                          \
                R[k].z * wa4.z + R[k].w * wa4.w;                           \
      lg[k] = wave_sum_b(p);                                               \
    }                                                                      \
    if (s_cur == s_end) {           /* fast: no boundary remains */        \
      float mt = lg[0];                                                    \
      _Pragma("unroll")                                                    \
      for (int k = 1; k < SUB; ++k) mt = fmaxf(mt, lg[k]);                 \
      const float mn = fmaxf(m, mt);                                       \
      const float sc = __expf(m - mn);   /* m=-inf -> 0 */                 \
      d *= sc;                                                             \
      acc.x *= sc; acc.y *= sc; acc.z *= sc; acc.w *= sc;                  \
      _Pragma("unroll")                                                    \
      for (int k = 0; k < SUB; ++k) {                                      \
        float e = __expf(lg[k] - mn);                                      \
        d += e;                                                            \
        acc.x = fmaf(e, R[k].x, acc.x);                                    \
        acc.y = fmaf(e, R[k].y, acc.y);                                    \
        acc.z = fmaf(e, R[k].z, acc.z);                                    \
        acc.w = fmaf(e, R[k].w, acc.w);                                    \
      }                                                                    \
      m = mn;                                                              \
    } else {                        /* boundary inside remainder */        \
      _Pragma("unroll")                                                    \
      for (int k = 0; k < SUB; ++k) {                                      \
        const int a = base + (t) * SUB + k;   /* wave-uniform */           \
        if (a >= hi_cur) {          /* crossed into next segment */        \
          FLUSH_PART();                                                    \
          m = -INFINITY; d = 0.f;                                          \
          acc = make_float4(0.f, 0.f, 0.f, 0.f);                           \
          s_cur += 1;                                                      \
          hi_cur = (int)load_off(offs_raw, s_cur + 1, is64);               \
        }                                                                  \
        const float mn = fmaxf(m, lg[k]);                                  \
        const float sc = __expf(m - mn);                                   \
        const float e  = __expf(lg[k] - mn);                               \
        d = fmaf(d, sc, e);                                                \
        acc.x = fmaf(acc.x, sc, e * R[k].x);                               \
        acc.y = fmaf(acc.y, sc, e * R[k].y);                               \
        acc.z = fmaf(acc.z, sc, e * R[k].z);                               \
        acc.w = fmaf(acc.w, sc, e * R[k].w);                               \
        m = mn;                                                            \
      }                                                                    \
    }                                                                      \
  } while (0)

  // 8 subtiles, A/B rotation: loads for subtile t+2 issue before proc(t)
  PROC_SUB(A, 0);
#pragma unroll
  for (int k = 0; k < SUB; ++k) A[k] = fg[(size_t)(2 * SUB + k) * 64 + lane];
  PROC_SUB(B, 1);
#pragma unroll
  for (int k = 0; k < SUB; ++k) B[k] = fg[(size_t)(3 * SUB + k) * 64 + lane];
  PROC_SUB(A, 2);
#pragma unroll
  for (int k = 0; k < SUB; ++k) A[k] = fg[(size_t)(4 * SUB + k) * 64 + lane];
  PROC_SUB(B, 3);
#pragma unroll
  for (int k = 0; k < SUB; ++k) B[k] = fg[(size_t)(5 * SUB + k) * 64 + lane];
  PROC_SUB(A, 4);
#pragma unroll
  for (int k = 0; k < SUB; ++k) A[k] = fg[(size_t)(6 * SUB + k) * 64 + lane];
  PROC_SUB(B, 5);
#pragma unroll
  for (int k = 0; k < SUB; ++k) B[k] = fg[(size_t)(7 * SUB + k) * 64 + lane];
  PROC_SUB(A, 6);
  PROC_SUB(B, 7);

  FLUSH_PART();                      // final partial (s_cur == s_end here)
#undef PROC_SUB
#undef FLUSH_PART
}

// wave-per-segment flash-merge (n <= ~21 slots at TA=64 -> one chunk) +
// block projection GEMM. Partials are bf16 (~3 MB total, L2-resident).
__global__ __launch_bounds__(256, 4)
void merge_project(const float* __restrict__ md,
                   const uint2* __restrict__ accbuf,
                   const void* __restrict__ offs_raw,
                   const float* __restrict__ Wo,
                   const float* __restrict__ bo,
                   float* __restrict__ out)
{
  __shared__ float pooled[4][DIM];
  __shared__ float sc_s[4][64];
  const int tid  = threadIdx.x;
  const int lane = tid & 63;
  const int wv   = tid >> 6;
  const int is64 = (((const int*)offs_raw)[1] == 0);
  const int s    = blockIdx.x * 4 + wv;

  {
    const int lo = (int)load_off(offs_raw, s, is64);
    const int hi = (int)load_off(offs_raw, s + 1, is64);
    const int u0 = lo / TA;
    const int u1 = (hi - 1) / TA;
    const int n  = u1 - u0 + 1;

    float M = -INFINITY, D = 0.f;
    float4 acc = make_float4(0.f, 0.f, 0.f, 0.f);

    for (int c0 = 0; c0 < n; c0 += 64) {
      const int j = c0 + lane;
      const bool v = (j < n);
      const int slot = s + u0 + j;
      float mj = v ? md[2 * slot] : -INFINITY;
      float dj = v ? md[2 * slot + 1] : 0.f;

      float Mc = mj;                     // chunk max -> all lanes
      Mc = fmaxf(Mc, __shfl_xor(Mc, 32));
      Mc = fmaxf(Mc, __shfl_xor(Mc, 16));
      Mc = fmaxf(Mc, __shfl_xor(Mc, 8));
      Mc = fmaxf(Mc, __shfl_xor(Mc, 4));
      Mc = fmaxf(Mc, __shfl_xor(Mc, 2));
      Mc = fmaxf(Mc, __shfl_xor(Mc, 1));
      const float Mn = fmaxf(M, Mc);
      const float rs = (c0 == 0) ? 0.f : __expf(M - Mn);  // avoid -inf - -inf
      const float scj = __expf(mj - Mn);                  // 0 for invalid lanes

      float t = dj * scj;                // chunk denom -> all lanes
      t += __shfl_xor(t, 32);
      t += __shfl_xor(t, 16);
      t += __shfl_xor(t, 8);
      t += __shfl_xor(t, 4);
      t += __shfl_xor(t, 2);
      t += __shfl_xor(t, 1);
      D = D * rs + t;

      sc_s[wv][lane] = scj;              // wave-coherent LDS stage

      acc.x *= rs; acc.y *= rs; acc.z *= rs; acc.w *= rs;

      const int cn = (n - c0) < 64 ? (n - c0) : 64;
      const uint2* ab = accbuf + (size_t)(s + u0 + c0) * 64;
      int jj = 0;
      for (; jj + 4 <= cn; jj += 4) {    // 4 independent 512-B reads in flight
        float4 a0 = unpack4(ab[(size_t)(jj + 0) * 64 + lane]);
        float4 a1 = unpack4(ab[(size_t)(jj + 1) * 64 + lane]);
        float4 a2 = unpack4(ab[(size_t)(jj + 2) * 64 + lane]);
        float4 a3 = unpack4(ab[(size_t)(jj + 3) * 64 + lane]);
        float s0 = sc_s[wv][jj + 0], s1 = sc_s[wv][jj + 1];
        float s2 = sc_s[wv][jj + 2], s3 = sc_s[wv][jj + 3];
        acc.x = fmaf(s0, a0.x, fmaf(s1, a1.x, fmaf(s2, a2.x, fmaf(s3, a3.x, acc.x))));
        acc.y = fmaf(s0, a0.y, fmaf(s1, a1.y, fmaf(s2, a2.y, fmaf(s3, a3.y, acc.y))));
        acc.z = fmaf(s0, a0.z, fmaf(s1, a1.z, fmaf(s2, a2.z, fmaf(s3, a3.z, acc.z))));
        acc.w = fmaf(s0, a0.w, fmaf(s1, a1.w, fmaf(s2, a2.w, fmaf(s3, a3.w, acc.w))));
      }
      for (; jj < cn; ++jj) {
        float4 a0 = unpack4(ab[(size_t)jj * 64 + lane]);
        float s0 = sc_s[wv][jj];
        acc.x = fmaf(s0, a0.x, acc.x);
        acc.y = fmaf(s0, a0.y, acc.y);
        acc.z = fmaf(s0, a0.z, acc.z);
        acc.w = fmaf(s0, a0.w, acc.w);
      }
      M = Mn;
    }

    const float inv = 1.f / D;
    ((float4*)pooled[wv])[lane] =
        make_float4(acc.x * inv, acc.y * inv, acc.z * inv, acc.w * inv);
  }
  __syncthreads();

  // out[4 x 256] = pooled @ Wo + bo ; thread owns output dim tid
  float o0 = 0.f, o1 = 0.f, o2 = 0.f, o3 = 0.f;
  for (int k = 0; k < DIM; ++k) {
    float w = Wo[k * DIM + tid];           // coalesced; Wo is L2-resident
    o0 = fmaf(pooled[0][k], w, o0);        // LDS broadcast reads
    o1 = fmaf(pooled[1][k], w, o1);
    o2 = fmaf(pooled[2][k], w, o2);
    o3 = fmaf(pooled[3][k], w, o3);
  }
  const float b = bo[tid];
  const int sb = blockIdx.x * 4;
  out[(size_t)(sb + 0) * DIM + tid] = o0 + b;
  out[(size_t)(sb + 1) * DIM + tid] = o1 + b;
  out[(size_t)(sb + 2) * DIM + tid] = o2 + b;
  out[(size_t)(sb + 3) * DIM + tid] = o3 + b;
}

extern "C" void kernel_launch(void* const* d_in, const int* in_sizes, int n_in,
                              void* d_out, int out_size, void* d_ws, size_t ws_size,
                              hipStream_t stream)
{
  const float* feat = (const float*)d_in[0];
  const void*  offs = d_in[1];
  const float* Wa   = (const float*)d_in[2];
  /* d_in[3] = ba: cancels under softmax shift invariance */
  const float* Wo   = (const float*)d_in[4];
  const float* bo   = (const float*)d_in[5];
  float* out = (float*)d_out;

  float* md     = (float*)d_ws;                    // [SLOTS][2] fp32
  uint2* accbuf = (uint2*)(md + 2 * SLOTS);        // [SLOTS][64] bf16x4
  int*   s0tab  = (int*)(accbuf + (size_t)SLOTS * 64);   // [NTILES]
  int*   s1tab  = s0tab + NTILES;                  // [NTILES]

  hipLaunchKernelGGL(seg_of_tile, dim3((NSEG + 255) / 256), dim3(256), 0, stream,
                     offs, s0tab, s1tab);
  hipLaunchKernelGGL(pool_waves, dim3(NBLK), dim3(256), 0, stream,
                     feat, offs, Wa, s0tab, s1tab, md, accbuf);
  hipLaunchKernelGGL(merge_project, dim3(NSEG / 4), dim3(256), 0, stream,
                     md, accbuf, offs, Wo, bo, out);
}

// Round 12
// 66.357 us; speedup vs baseline: 1.0504x; 1.0504x over previous
//
#include <hip/hip_runtime.h>

#define DIM 256
#define NSEG 2048
#define NATOMS 262144
#define SUB 8                         /* atoms per subtile (R7-proven unit) */
#define NSUB 4
#define TA (SUB * NSUB)               /* 32 atoms per wave-tile */
#define NTILES (NATOMS / TA)          /* 8192, exact */
#define SLOTS (NSEG + NTILES)         /* 10240 */
#define WPB 4                         /* waves per block */
#define NBLK (NTILES / WPB)           /* 2048 = 8 blocks/CU: 2 rounds, balanced */

// index_list may arrive as int64 (reference dtype) or int32. Detect on-device:
// for int64, word[1] is the high half of offset 0 (== 0); for int32, word[1]
// is the first interior offset (>= 1).
__device__ __forceinline__ long long load_off(const void* p, int i, int is64) {
  if (is64) return ((const long long*)p)[i];
  return (long long)((const int*)p)[i];
}

// Wave-wide sum, result broadcast to ALL lanes. DPP (VALU pipe) for strides
// 1,2,4,8; ds_swizzle for 16; shfl for 32. Validated R5-R11.
__device__ __forceinline__ float wave_sum_b(float v) {
  int x;
  x = __builtin_amdgcn_update_dpp(0, __float_as_int(v), 0xB1, 0xF, 0xF, true);
  v += __int_as_float(x);
  x = __builtin_amdgcn_update_dpp(0, __float_as_int(v), 0x4E, 0xF, 0xF, true);
  v += __int_as_float(x);
  x = __builtin_amdgcn_update_dpp(0, __float_as_int(v), 0x141, 0xF, 0xF, true);
  v += __int_as_float(x);
  x = __builtin_amdgcn_update_dpp(0, __float_as_int(v), 0x140, 0xF, 0xF, true);
  v += __int_as_float(x);
  v += __int_as_float(__builtin_amdgcn_ds_swizzle(__float_as_int(v), 0x401F));
  v += __shfl_xor(v, 32);
  return v;
}

// fp32 -> bf16 (RNE) pack / unpack (validated R7-R11, absmax 0.0156 << 0.0675).
__device__ __forceinline__ unsigned bf16rne(float f) {
  unsigned u = __float_as_uint(f);
  return (u + 0x7FFFu + ((u >> 16) & 1u)) >> 16;
}
__device__ __forceinline__ unsigned pack2(float a, float b) {
  return bf16rne(a) | (bf16rne(b) << 16);
}
__device__ __forceinline__ float4 unpack4(uint2 u) {
  float4 f;
  f.x = __uint_as_float(u.x << 16);
  f.y = __uint_as_float(u.x & 0xFFFF0000u);
  f.z = __uint_as_float(u.y << 16);
  f.w = __uint_as_float(u.y & 0xFFFF0000u);
  return f;
}

// s0tab[u]/s1tab[u] = segment of tile u's first/last atom.
__global__ void seg_of_tile(const void* __restrict__ offs_raw,
                            int* __restrict__ s0tab,
                            int* __restrict__ s1tab)
{
  int s = blockIdx.x * blockDim.x + threadIdx.x;
  if (s >= NSEG) return;
  const int is64 = (((const int*)offs_raw)[1] == 0);
  const int lo = (int)load_off(offs_raw, s, is64);
  const int hi = (int)load_off(offs_raw, s + 1, is64);
  {
    int u0 = (lo + TA - 1) / TA;
    int u1 = (hi + TA - 1) / TA - 1;
    for (int u = u0; u <= u1; ++u) s0tab[u] = s;
  }
  {
    int u0 = lo / TA;
    int u1 = hi >= TA ? (hi - TA) / TA : -1;
    for (int u = u0; u <= u1; ++u) s1tab[u] = s;
  }
}

// Online-softmax pooling (R10-best): 32-atom tile as 4 subtiles of 8, running
// (m,d,acc) in registers (flash rescale per subtile). One partial per
// (segment,tile) intersection. A/B subtile double-buffer keeps 8 loads in
// flight under compute; ~100 VGPR < 128 cap (4 blk/CU).
__global__ __launch_bounds__(256, 4)
void pool_waves(const float* __restrict__ feat,
                const void* __restrict__ offs_raw,
                const float* __restrict__ Wa,
                const int* __restrict__ s0tab,
                const int* __restrict__ s1tab,
                float* __restrict__ md,
                uint2* __restrict__ accbuf)
{
  const int lane = threadIdx.x & 63;
  const int wv   = threadIdx.x >> 6;
  const int u    = blockIdx.x * WPB + wv;
  const int base = u * TA;
  const int is64 = (((const int*)offs_raw)[1] == 0);

  const float4* fg = (const float4*)feat + (size_t)base * (DIM / 4);

  float4 A[SUB], B[SUB];
#pragma unroll
  for (int k = 0; k < SUB; ++k) A[k] = fg[(size_t)k * 64 + lane];        // sub 0
#pragma unroll
  for (int k = 0; k < SUB; ++k) B[k] = fg[(size_t)(SUB + k) * 64 + lane]; // sub 1

  int s_cur = s0tab[u];
  const int s_end = s1tab[u];
  const float4 wa4 = ((const float4*)Wa)[lane];
  int hi_cur = (int)load_off(offs_raw, s_cur + 1, is64);  // uniform, L2-hot

  float m = -INFINITY, d = 0.f;
  float4 acc = make_float4(0.f, 0.f, 0.f, 0.f);

#define FLUSH_PART() do {                                                  \
    const int slot_ = s_cur + u;      /* injective: s+u monotone */        \
    accbuf[(size_t)slot_ * 64 + lane] =                                    \
        make_uint2(pack2(acc.x, acc.y), pack2(acc.z, acc.w));              \
    if (lane == 0) *((float2*)(md + 2 * slot_)) = make_float2(m, d);       \
  } while (0)

#define PROC_SUB(R, t) do {                                                \
    float lg[SUB];                                                         \
    _Pragma("unroll")                                                      \
    for (int k = 0; k < SUB; ++k) {                                        \
      float p = R[k].x * wa4.x + R[k].y * wa4.y +                          \
                R[k].z * wa4.z + R[k].w * wa4.w;                           \
      lg[k] = wave_sum_b(p);                                               \
    }                                                                      \
    if (s_cur == s_end) {           /* fast: no boundary remains */        \
      float mt = lg[0];                                                    \
      _Pragma("unroll")                                                    \
      for (int k = 1; k < SUB; ++k) mt = fmaxf(mt, lg[k]);                 \
      const float mn = fmaxf(m, mt);                                       \
      const float sc = __expf(m - mn);   /* m=-inf -> 0 */                 \
      d *= sc;                                                             \
      acc.x *= sc; acc.y *= sc; acc.z *= sc; acc.w *= sc;                  \
      _Pragma("unroll")                                                    \
      for (int k = 0; k < SUB; ++k) {                                      \
        float e = __expf(lg[k] - mn);                                      \
        d += e;                                                            \
        acc.x = fmaf(e, R[k].x, acc.x);                                    \
        acc.y = fmaf(e, R[k].y, acc.y);                                    \
        acc.z = fmaf(e, R[k].z, acc.z);                                    \
        acc.w = fmaf(e, R[k].w, acc.w);                                    \
      }                                                                    \
      m = mn;                                                              \
    } else {                        /* boundary inside remainder */        \
      _Pragma("unroll")                                                    \
      for (int k = 0; k < SUB; ++k) {                                      \
        const int a = base + (t) * SUB + k;   /* wave-uniform */           \
        if (a >= hi_cur) {          /* crossed into next segment */        \
          FLUSH_PART();                                                    \
          m = -INFINITY; d = 0.f;                                          \
          acc = make_float4(0.f, 0.f, 0.f, 0.f);                           \
          s_cur += 1;                                                      \
          hi_cur = (int)load_off(offs_raw, s_cur + 1, is64);               \
        }                                                                  \
        const float mn = fmaxf(m, lg[k]);                                  \
        const float sc = __expf(m - mn);                                   \
        const float e  = __expf(lg[k] - mn);                               \
        d = fmaf(d, sc, e);                                                \
        acc.x = fmaf(acc.x, sc, e * R[k].x);                               \
        acc.y = fmaf(acc.y, sc, e * R[k].y);                               \
        acc.z = fmaf(acc.z, sc, e * R[k].z);                               \
        acc.w = fmaf(acc.w, sc, e * R[k].w);                               \
        m = mn;                                                            \
      }                                                                    \
    }                                                                      \
  } while (0)

  PROC_SUB(A, 0);
#pragma unroll
  for (int k = 0; k < SUB; ++k) A[k] = fg[(size_t)(2 * SUB + k) * 64 + lane];
  PROC_SUB(B, 1);
#pragma unroll
  for (int k = 0; k < SUB; ++k) B[k] = fg[(size_t)(3 * SUB + k) * 64 + lane];
  PROC_SUB(A, 2);
  PROC_SUB(B, 3);

  FLUSH_PART();                      // final partial (s_cur == s_end here)
#undef PROC_SUB
#undef FLUSH_PART
}

// wave-per-segment flash-merge (n <= ~42 slots -> single chunk of 64) +
// block projection GEMM. Partials are bf16 (5.2 MB total, L2-resident).
__global__ __launch_bounds__(256, 4)
void merge_project(const float* __restrict__ md,
                   const uint2* __restrict__ accbuf,
                   const void* __restrict__ offs_raw,
                   const float* __restrict__ Wo,
                   const float* __restrict__ bo,
                   float* __restrict__ out)
{
  __shared__ float pooled[4][DIM];
  __shared__ float sc_s[4][64];
  const int tid  = threadIdx.x;
  const int lane = tid & 63;
  const int wv   = tid >> 6;
  const int is64 = (((const int*)offs_raw)[1] == 0);
  const int s    = blockIdx.x * 4 + wv;

  {
    const int lo = (int)load_off(offs_raw, s, is64);
    const int hi = (int)load_off(offs_raw, s + 1, is64);
    const int u0 = lo / TA;
    const int u1 = (hi - 1) / TA;
    const int n  = u1 - u0 + 1;

    float M = -INFINITY, D = 0.f;
    float4 acc = make_float4(0.f, 0.f, 0.f, 0.f);

    for (int c0 = 0; c0 < n; c0 += 64) {
      const int j = c0 + lane;
      const bool v = (j < n);
      const int slot = s + u0 + j;
      float mj = v ? md[2 * slot] : -INFINITY;
      float dj = v ? md[2 * slot + 1] : 0.f;

      float Mc = mj;                     // chunk max -> all lanes
      Mc = fmaxf(Mc, __shfl_xor(Mc, 32));
      Mc = fmaxf(Mc, __shfl_xor(Mc, 16));
      Mc = fmaxf(Mc, __shfl_xor(Mc, 8));
      Mc = fmaxf(Mc, __shfl_xor(Mc, 4));
      Mc = fmaxf(Mc, __shfl_xor(Mc, 2));
      Mc = fmaxf(Mc, __shfl_xor(Mc, 1));
      const float Mn = fmaxf(M, Mc);
      const float rs = (c0 == 0) ? 0.f : __expf(M - Mn);  // avoid -inf - -inf
      const float scj = __expf(mj - Mn);                  // 0 for invalid lanes

      float t = dj * scj;                // chunk denom -> all lanes
      t += __shfl_xor(t, 32);
      t += __shfl_xor(t, 16);
      t += __shfl_xor(t, 8);
      t += __shfl_xor(t, 4);
      t += __shfl_xor(t, 2);
      t += __shfl_xor(t, 1);
      D = D * rs + t;

      sc_s[wv][lane] = scj;              // wave-coherent LDS stage

      acc.x *= rs; acc.y *= rs; acc.z *= rs; acc.w *= rs;

      const int cn = (n - c0) < 64 ? (n - c0) : 64;
      const uint2* ab = accbuf + (size_t)(s + u0 + c0) * 64;
      int jj = 0;
      for (; jj + 4 <= cn; jj += 4) {    // 4 independent 512-B reads in flight
        float4 a0 = unpack4(ab[(size_t)(jj + 0) * 64 + lane]);
        float4 a1 = unpack4(ab[(size_t)(jj + 1) * 64 + lane]);
        float4 a2 = unpack4(ab[(size_t)(jj + 2) * 64 + lane]);
        float4 a3 = unpack4(ab[(size_t)(jj + 3) * 64 + lane]);
        float s0 = sc_s[wv][jj + 0], s1 = sc_s[wv][jj + 1];
        float s2 = sc_s[wv][jj + 2], s3 = sc_s[wv][jj + 3];
        acc.x = fmaf(s0, a0.x, fmaf(s1, a1.x, fmaf(s2, a2.x, fmaf(s3, a3.x, acc.x))));
        acc.y = fmaf(s0, a0.y, fmaf(s1, a1.y, fmaf(s2, a2.y, fmaf(s3, a3.y, acc.y))));
        acc.z = fmaf(s0, a0.z, fmaf(s1, a1.z, fmaf(s2, a2.z, fmaf(s3, a3.z, acc.z))));
        acc.w = fmaf(s0, a0.w, fmaf(s1, a1.w, fmaf(s2, a2.w, fmaf(s3, a3.w, acc.w))));
      }
      for (; jj < cn; ++jj) {
        float4 a0 = unpack4(ab[(size_t)jj * 64 + lane]);
        float s0 = sc_s[wv][jj];
        acc.x = fmaf(s0, a0.x, acc.x);
        acc.y = fmaf(s0, a0.y, acc.y);
        acc.z = fmaf(s0, a0.z, acc.z);
        acc.w = fmaf(s0, a0.w, acc.w);
      }
      M = Mn;
    }

    const float inv = 1.f / D;
    ((float4*)pooled[wv])[lane] =
        make_float4(acc.x * inv, acc.y * inv, acc.z * inv, acc.w * inv);
  }
  __syncthreads();

  // out[4 x 256] = pooled @ Wo + bo ; thread owns output dim tid
  float o0 = 0.f, o1 = 0.f, o2 = 0.f, o3 = 0.f;
  for (int k = 0; k < DIM; ++k) {
    float w = Wo[k * DIM + tid];           // coalesced; Wo is L2-resident
    o0 = fmaf(pooled[0][k], w, o0);        // LDS broadcast reads
    o1 = fmaf(pooled[1][k], w, o1);
    o2 = fmaf(pooled[2][k], w, o2);
    o3 = fmaf(pooled[3][k], w, o3);
  }
  const float b = bo[tid];
  const int sb = blockIdx.x * 4;
  out[(size_t)(sb + 0) * DIM + tid] = o0 + b;
  out[(size_t)(sb + 1) * DIM + tid] = o1 + b;
  out[(size_t)(sb + 2) * DIM + tid] = o2 + b;
  out[(size_t)(sb + 3) * DIM + tid] = o3 + b;
}

extern "C" void kernel_launch(void* const* d_in, const int* in_sizes, int n_in,
                              void* d_out, int out_size, void* d_ws, size_t ws_size,
                              hipStream_t stream)
{
  const float* feat = (const float*)d_in[0];
  const void*  offs = d_in[1];
  const float* Wa   = (const float*)d_in[2];
  /* d_in[3] = ba: cancels under softmax shift invariance */
  const float* Wo   = (const float*)d_in[4];
  const float* bo   = (const float*)d_in[5];
  float* out = (float*)d_out;

  float* md     = (float*)d_ws;                    // [SLOTS][2] fp32
  uint2* accbuf = (uint2*)(md + 2 * SLOTS);        // [SLOTS][64] bf16x4
  int*   s0tab  = (int*)(accbuf + (size_t)SLOTS * 64);   // [NTILES]
  int*   s1tab  = s0tab + NTILES;                  // [NTILES]

  hipLaunchKernelGGL(seg_of_tile, dim3((NSEG + 255) / 256), dim3(256), 0, stream,
                     offs, s0tab, s1tab);
  hipLaunchKernelGGL(pool_waves, dim3(NBLK), dim3(256), 0, stream,
                     feat, offs, Wa, s0tab, s1tab, md, accbuf);
  hipLaunchKernelGGL(merge_project, dim3(NSEG / 4), dim3(256), 0, stream,
                     md, accbuf, offs, Wo, bo, out);
}